// Round 1
// baseline (288.299 us; speedup 1.0000x reference)
//
#include <hip/hip_runtime.h>
#include <stdint.h>

// OFT injected linear, algebraically reduced:
//   delta is DIAGONAL (identity elementwise-multiplied by block-diag factors)
//   diag(Q) for Q=(I-S)(I+S)^-1, S skew  =>  1 - 2*sum_j S_ij^2  (odd powers have 0 diag)
//   out = input @ (diag(v) W^T)  -- one bf16 MFMA GEMM + cheap prologue.

typedef __bf16 bf16;
typedef __bf16 bf16x4 __attribute__((ext_vector_type(4)));
typedef __bf16 bf16x8 __attribute__((ext_vector_type(8)));
typedef float  f32x4  __attribute__((ext_vector_type(4)));

#define AS1 __attribute__((address_space(1)))
#define AS3 __attribute__((address_space(3)))

// ---- workspace layout (bytes) ----
constexpr size_t OFF_INBF = 0;                                   // 4096*4096 bf16 = 33554432
constexpr size_t OFF_WV   = OFF_INBF + (size_t)4096 * 4096 * 2;  // 33554432
constexpr size_t OFF_MEAN = OFF_WV + (size_t)4096 * 4096 * 2;    // 4096 f32
constexpr size_t OFF_T    = OFF_MEAN + 4096 * 4;                 // 8*1024 f32
constexpr size_t OFF_NRM2 = OFF_T + 8 * 1024 * 4;                // 8 f32 (pad 64)
constexpr size_t OFF_INFO = OFF_NRM2 + 64;                       // 4 words
constexpr size_t OFF_V    = OFF_INFO + 64;                       // 4096 f32

// ---------------- K1: column mean over SEQ + fp32->bf16 convert ----------------
__global__ void mean_cvt(const float4* __restrict__ in4, float* __restrict__ meansum,
                         bf16* __restrict__ ob) {
    const int t  = threadIdx.x;
    const int f4 = blockIdx.x * 256 + t;      // 0..1023 (4 cols each)
    const int s0 = blockIdx.y * 32;           // 128 y-blocks * 32 rows
    float sx = 0.f, sy = 0.f, sz = 0.f, sw = 0.f;
    for (int s = s0; s < s0 + 32; ++s) {
        float4 vx = in4[(size_t)s * 1024 + f4];
        sx += vx.x; sy += vx.y; sz += vx.z; sw += vx.w;
        bf16x4 bv;
        bv[0] = (bf16)vx.x; bv[1] = (bf16)vx.y; bv[2] = (bf16)vx.z; bv[3] = (bf16)vx.w;
        *(bf16x4*)&ob[(size_t)s * 4096 + f4 * 4] = bv;
    }
    atomicAdd(&meansum[f4 * 4 + 0], sx);
    atomicAdd(&meansum[f4 * 4 + 1], sy);
    atomicAdd(&meansum[f4 * 4 + 2], sz);
    atomicAdd(&meansum[f4 * 4 + 3], sw);
}

// ---------------- K2: logits -> softmax -> top-k selection ----------------
__global__ void omega_kernel(const float* __restrict__ meansum, const float* __restrict__ lora_route,
                             const int* __restrict__ task_id_p, int* __restrict__ info_i,
                             float* __restrict__ info_f) {
    __shared__ float red[256];
    __shared__ float logits[5];
    const int t = threadIdx.x;
    const int tid = task_id_p[0];
    const float* route = lora_route + (size_t)(tid - 1) * 4096 * 5;
    float acc[5] = {0.f, 0.f, 0.f, 0.f, 0.f};
    for (int f = t; f < 4096; f += 256) {
        float m = meansum[f] * (1.0f / 4096.0f);
#pragma unroll
        for (int p = 0; p < 5; ++p) acc[p] += m * route[f * 5 + p];
    }
    for (int p = 0; p < 5; ++p) {
        red[t] = acc[p];
        __syncthreads();
        for (int s = 128; s > 0; s >>= 1) {
            if (t < s) red[t] += red[t + s];
            __syncthreads();
        }
        if (t == 0) logits[p] = red[0];
        __syncthreads();
    }
    if (t == 0) {
        float mx = logits[0];
        for (int p = 1; p < 5; ++p) mx = fmaxf(mx, logits[p]);
        float e[5], se = 0.f;
        for (int p = 0; p < 5; ++p) { e[p] = expf(logits[p] - mx); se += e[p]; }
        float om[5];
        for (int p = 0; p < 5; ++p) om[p] = e[p] / se;
        const int n = tid < 5 ? tid : 5;           // omegas_mean[:task_id]
        int j1 = 0;
        for (int p = 1; p < n; ++p) if (om[p] > om[j1]) j1 = p;
        int j2 = -1;
        for (int p = 0; p < n; ++p) if (p != j1 && (j2 < 0 || om[p] > om[j2])) j2 = p;
        const int k = tid < 2 ? tid : 2;           // min(task_id, 2)
        info_i[0] = j1;
        info_i[1] = (k > 1) ? j2 : j1;
        info_i[2] = k;
        float c = om[j1];
        if (k > 1) c *= om[j2];
        info_f[3] = c;
    }
}

// ---------------- K3: per selected task/block: T[i]=sum_j (R_ij - R_ji)^2, nrm2 ----------------
__global__ void diag_kernel(const float* __restrict__ lora_down, const int* __restrict__ info_i,
                            float* __restrict__ T, float* __restrict__ nrm2) {
    const int bid = blockIdx.x;
    const int ts = bid >> 6;          // task slot 0..1
    const int rb = (bid >> 4) & 3;    // block 0..3
    const int a  = bid & 15;          // row tile 0..15
    const int k = info_i[2];
    if (ts >= k) return;
    const int j = info_i[ts];
    const float* R = lora_down + ((size_t)(j * 4 + rb) << 20);
    __shared__ float X[64][65];
    __shared__ float Y[64][65];
    const int t = threadIdx.x;
    const int i = t >> 2, g = t & 3;
    const int a64 = a * 64;
    float tacc = 0.f, nacc = 0.f;
    for (int b = 0; b < 16; ++b) {
        __syncthreads();
#pragma unroll
        for (int q = 0; q < 4; ++q) {
            const int fi = q * 256 + t;
            const int row = fi >> 4, c4 = fi & 15;
            float4 vx = *(const float4*)&R[(size_t)(a64 + row) * 1024 + b * 64 + c4 * 4];
            X[row][c4 * 4 + 0] = vx.x; X[row][c4 * 4 + 1] = vx.y;
            X[row][c4 * 4 + 2] = vx.z; X[row][c4 * 4 + 3] = vx.w;
            nacc += vx.x * vx.x + vx.y * vx.y + vx.z * vx.z + vx.w * vx.w;
            float4 vy = *(const float4*)&R[(size_t)(b * 64 + row) * 1024 + a64 + c4 * 4];
            Y[row][c4 * 4 + 0] = vy.x; Y[row][c4 * 4 + 1] = vy.y;
            Y[row][c4 * 4 + 2] = vy.z; Y[row][c4 * 4 + 3] = vy.w;
        }
        __syncthreads();
#pragma unroll
        for (int s = 0; s < 16; ++s) {
            float xv = X[i][g * 16 + s];
            float yv = Y[g * 16 + s][i];
            float d = xv - yv;
            tacc += d * d;
        }
    }
    tacc += __shfl_xor(tacc, 1);
    tacc += __shfl_xor(tacc, 2);
    if (g == 0) T[((ts * 4 + rb) << 10) + a64 + i] = tacc;
    for (int off = 32; off > 0; off >>= 1) nacc += __shfl_down(nacc, off);
    if ((t & 63) == 0) atomicAdd(&nrm2[ts * 4 + rb], nacc);
}

// ---------------- K4: v[i] = c * prod_ts (1 - 0.5*scale^2*T) ----------------
__global__ void vbuild(const float* __restrict__ T, const float* __restrict__ nrm2,
                       const int* __restrict__ info_i, const float* __restrict__ info_f,
                       float* __restrict__ v) {
    const int i = blockIdx.x * 256 + threadIdx.x;   // 0..4095
    const int k = info_i[2];
    const float c = info_f[3];
    const int rb = i >> 10, di = i & 1023;
    const float eps = 1e-5f * 1024.0f * 1024.0f / 2.0f;   // EPS0*d*d/sqrt(r)
    float q = c;
    for (int ts = 0; ts < k; ++ts) {
        float nrm = sqrtf(nrm2[ts * 4 + rb]);
        float scale = (nrm <= eps) ? 1.0f : eps / fmaxf(nrm, 1e-12f);
        q *= 1.0f - 0.5f * scale * scale * T[((ts * 4 + rb) << 10) + di];
    }
    v[i] = q;
}

// ---------------- K5: Wv[o][i] = bf16(W[o][i] * v[i]) ----------------
__global__ void scaleW(const float4* __restrict__ W4, const float* __restrict__ v,
                       bf16* __restrict__ Wv) {
    const size_t stride = (size_t)gridDim.x * blockDim.x;
    for (size_t i = (size_t)blockIdx.x * blockDim.x + threadIdx.x; i < (size_t)4096 * 1024; i += stride) {
        float4 w = W4[i];
        const float* vp = &v[(i & 1023) << 2];
        bf16x4 o;
        o[0] = (bf16)(w.x * vp[0]);
        o[1] = (bf16)(w.y * vp[1]);
        o[2] = (bf16)(w.z * vp[2]);
        o[3] = (bf16)(w.w * vp[3]);
        *(bf16x4*)&Wv[i << 2] = o;
    }
}

// ---------------- K6: C[4096][4096] f32 = A[4096][4096]bf16 @ B[4096][4096]bf16^T ----------------
__device__ __forceinline__ void gload_lds16(const bf16* g, bf16* lds) {
    __builtin_amdgcn_global_load_lds((const AS1 void*)g, (AS3 void*)lds, 16, 0, 0);
}

__global__ __launch_bounds__(256) void gemm_bt(const bf16* __restrict__ A, const bf16* __restrict__ B,
                                               float* __restrict__ C) {
    __shared__ bf16 lA[128 * 32];
    __shared__ bf16 lB[128 * 32];
    const int t = threadIdx.x;
    const int w = t >> 6, l = t & 63;
    const int bm = blockIdx.y, bn = blockIdx.x;
    const int wm = w >> 1, wn = w & 1;
    // staging: thread covers 8 bf16 (16B); chunk c covers 64 rows
    const int srow = t >> 2;
    const int scol = (t & 3) << 3;
    const bf16* Ag0 = A + (size_t)(bm * 128 + srow) * 4096 + scol;
    const bf16* Bg0 = B + (size_t)(bn * 128 + srow) * 4096 + scol;
    bf16* lA0 = &lA[w * 512];
    bf16* lA1 = &lA[2048 + w * 512];
    bf16* lB0 = &lB[w * 512];
    bf16* lB1 = &lB[2048 + w * 512];
    // fragment read offsets (A-frag: row=l%16, k=(l/16)*8)
    const int fr = l & 15;
    const int fk = (l >> 4) << 3;
    const int aoff0 = (wm * 64 + fr) * 32 + fk;
    const int boff0 = (wn * 64 + fr) * 32 + fk;
    f32x4 acc[4][4] = {};
    for (int kt = 0; kt < 128; ++kt) {
        const int k0 = kt << 5;
        gload_lds16(Ag0 + k0, lA0);
        gload_lds16(Ag0 + 64 * 4096 + k0, lA1);
        gload_lds16(Bg0 + k0, lB0);
        gload_lds16(Bg0 + 64 * 4096 + k0, lB1);
        __syncthreads();
        bf16x8 af[4], bg[4];
#pragma unroll
        for (int mi = 0; mi < 4; ++mi) af[mi] = *(const bf16x8*)&lA[aoff0 + mi * 512];
#pragma unroll
        for (int ni = 0; ni < 4; ++ni) bg[ni] = *(const bf16x8*)&lB[boff0 + ni * 512];
#pragma unroll
        for (int mi = 0; mi < 4; ++mi)
#pragma unroll
            for (int ni = 0; ni < 4; ++ni)
                acc[mi][ni] = __builtin_amdgcn_mfma_f32_16x16x32_bf16(af[mi], bg[ni], acc[mi][ni], 0, 0, 0);
        __syncthreads();
    }
    // C layout: row = (l>>4)*4 + reg, col = l&15  (m89-verified)
    const int crow = bm * 128 + wm * 64 + ((l >> 4) << 2);
    const int ccol = bn * 128 + wn * 64 + fr;
#pragma unroll
    for (int mi = 0; mi < 4; ++mi)
#pragma unroll
        for (int ni = 0; ni < 4; ++ni)
#pragma unroll
            for (int r = 0; r < 4; ++r)
                C[(size_t)(crow + mi * 16 + r) * 4096 + ccol + ni * 16] = acc[mi][ni][r];
}

extern "C" void kernel_launch(void* const* d_in, const int* in_sizes, int n_in,
                              void* d_out, int out_size, void* d_ws, size_t ws_size,
                              hipStream_t stream) {
    const float* input      = (const float*)d_in[0];
    const float* lora_route = (const float*)d_in[1];
    const float* lora_down  = (const float*)d_in[2];
    const float* W          = (const float*)d_in[3];
    const int*   task_id    = (const int*)d_in[4];

    char* ws = (char*)d_ws;
    bf16*  inbf    = (bf16*)(ws + OFF_INBF);
    bf16*  Wv      = (bf16*)(ws + OFF_WV);
    float* meansum = (float*)(ws + OFF_MEAN);
    float* T       = (float*)(ws + OFF_T);
    float* nrm2    = (float*)(ws + OFF_NRM2);
    int*   info_i  = (int*)(ws + OFF_INFO);
    float* info_f  = (float*)(ws + OFF_INFO);
    float* v       = (float*)(ws + OFF_V);
    float* out     = (float*)d_out;

    // zero mean accumulator + nrm2 (+T/info/v, harmless)
    hipMemsetAsync(ws + OFF_MEAN, 0, OFF_V + 4096 * 4 - OFF_MEAN, stream);

    mean_cvt<<<dim3(4, 128), 256, 0, stream>>>((const float4*)input, meansum, inbf);
    omega_kernel<<<1, 256, 0, stream>>>(meansum, lora_route, task_id, info_i, info_f);
    diag_kernel<<<128, 256, 0, stream>>>(lora_down, info_i, T, nrm2);
    vbuild<<<16, 256, 0, stream>>>(T, nrm2, info_i, info_f, v);
    scaleW<<<4096, 256, 0, stream>>>((const float4*)W, v, Wv);
    gemm_bt<<<dim3(32, 32), 256, 0, stream>>>(inbf, Wv, out);
}

// Round 3
// 210.776 us; speedup vs baseline: 1.3678x; 1.3678x over previous
//
#include <hip/hip_runtime.h>
#include <stdint.h>

// OFT injected linear, algebraically reduced:
//   delta is DIAGONAL (identity elementwise-multiplied by block-diag factors)
//   diag(Q) for Q=(I-S)(I+S)^-1, S skew  =>  1 - 2*sum_j S_ij^2  (odd powers have 0 diag)
//   out = input @ (diag(v) W^T)  -- one bf16 MFMA GEMM + cheap prologue.
// GEMM: 256x256 tile, BK=64, 8 waves, double-buffered LDS (128 KiB),
// T2 XOR-swizzle + T3/T4 counted vmcnt + T5 setprio + T1 XCD swizzle.

typedef __bf16 bf16;
typedef __bf16 bf16x4 __attribute__((ext_vector_type(4)));
typedef __bf16 bf16x8 __attribute__((ext_vector_type(8)));
typedef float  f32x4  __attribute__((ext_vector_type(4)));

#define AS1 __attribute__((address_space(1)))
#define AS3 __attribute__((address_space(3)))

// ---- workspace layout (bytes) ----
constexpr size_t OFF_INBF = 0;                                   // 4096*4096 bf16
constexpr size_t OFF_WV   = OFF_INBF + (size_t)4096 * 4096 * 2;
constexpr size_t OFF_MEAN = OFF_WV + (size_t)4096 * 4096 * 2;    // 4096 f32
constexpr size_t OFF_T    = OFF_MEAN + 4096 * 4;                 // 8*1024 f32
constexpr size_t OFF_NRM2 = OFF_T + 8 * 1024 * 4;                // 8 f32 (pad 64)
constexpr size_t OFF_INFO = OFF_NRM2 + 64;                       // 4 words
constexpr size_t OFF_V    = OFF_INFO + 64;                       // 4096 f32

// ---------------- K1: column mean over SEQ + fp32->bf16 convert ----------------
__global__ void mean_cvt(const float4* __restrict__ in4, float* __restrict__ meansum,
                         bf16* __restrict__ ob) {
    const int t  = threadIdx.x;
    const int f4 = blockIdx.x * 256 + t;
    const int s0 = blockIdx.y * 32;
    float sx = 0.f, sy = 0.f, sz = 0.f, sw = 0.f;
    for (int s = s0; s < s0 + 32; ++s) {
        float4 vx = in4[(size_t)s * 1024 + f4];
        sx += vx.x; sy += vx.y; sz += vx.z; sw += vx.w;
        bf16x4 bv;
        bv[0] = (bf16)vx.x; bv[1] = (bf16)vx.y; bv[2] = (bf16)vx.z; bv[3] = (bf16)vx.w;
        *(bf16x4*)&ob[(size_t)s * 4096 + f4 * 4] = bv;
    }
    atomicAdd(&meansum[f4 * 4 + 0], sx);
    atomicAdd(&meansum[f4 * 4 + 1], sy);
    atomicAdd(&meansum[f4 * 4 + 2], sz);
    atomicAdd(&meansum[f4 * 4 + 3], sw);
}

// ---------------- K2: logits -> softmax -> top-k selection ----------------
__global__ void omega_kernel(const float* __restrict__ meansum, const float* __restrict__ lora_route,
                             const int* __restrict__ task_id_p, int* __restrict__ info_i,
                             float* __restrict__ info_f) {
    __shared__ float red[256];
    __shared__ float logits[5];
    const int t = threadIdx.x;
    const int tid = task_id_p[0];
    const float* route = lora_route + (size_t)(tid - 1) * 4096 * 5;
    float acc[5] = {0.f, 0.f, 0.f, 0.f, 0.f};
    for (int f = t; f < 4096; f += 256) {
        float m = meansum[f] * (1.0f / 4096.0f);
#pragma unroll
        for (int p = 0; p < 5; ++p) acc[p] += m * route[f * 5 + p];
    }
    for (int p = 0; p < 5; ++p) {
        red[t] = acc[p];
        __syncthreads();
        for (int s = 128; s > 0; s >>= 1) {
            if (t < s) red[t] += red[t + s];
            __syncthreads();
        }
        if (t == 0) logits[p] = red[0];
        __syncthreads();
    }
    if (t == 0) {
        float mx = logits[0];
        for (int p = 1; p < 5; ++p) mx = fmaxf(mx, logits[p]);
        float e[5], se = 0.f;
        for (int p = 0; p < 5; ++p) { e[p] = expf(logits[p] - mx); se += e[p]; }
        float om[5];
        for (int p = 0; p < 5; ++p) om[p] = e[p] / se;
        const int n = tid < 5 ? tid : 5;
        int j1 = 0;
        for (int p = 1; p < n; ++p) if (om[p] > om[j1]) j1 = p;
        int j2 = -1;
        for (int p = 0; p < n; ++p) if (p != j1 && (j2 < 0 || om[p] > om[j2])) j2 = p;
        const int k = tid < 2 ? tid : 2;
        info_i[0] = j1;
        info_i[1] = (k > 1) ? j2 : j1;
        info_i[2] = k;
        float c = om[j1];
        if (k > 1) c *= om[j2];
        info_f[3] = c;
    }
}

// ---------------- K3: per selected task/block: T[i]=sum_j (R_ij - R_ji)^2, nrm2 ----------------
__global__ void diag_kernel(const float* __restrict__ lora_down, const int* __restrict__ info_i,
                            float* __restrict__ T, float* __restrict__ nrm2) {
    const int bid = blockIdx.x;
    const int ts = bid >> 6;
    const int rb = (bid >> 4) & 3;
    const int a  = bid & 15;
    const int k = info_i[2];
    if (ts >= k) return;
    const int j = info_i[ts];
    const float* R = lora_down + ((size_t)(j * 4 + rb) << 20);
    __shared__ float X[64][65];
    __shared__ float Y[64][65];
    const int t = threadIdx.x;
    const int i = t >> 2, g = t & 3;
    const int a64 = a * 64;
    float tacc = 0.f, nacc = 0.f;
    for (int b = 0; b < 16; ++b) {
        __syncthreads();
#pragma unroll
        for (int qq = 0; qq < 4; ++qq) {
            const int fi = qq * 256 + t;
            const int row = fi >> 4, c4 = fi & 15;
            float4 vx = *(const float4*)&R[(size_t)(a64 + row) * 1024 + b * 64 + c4 * 4];
            X[row][c4 * 4 + 0] = vx.x; X[row][c4 * 4 + 1] = vx.y;
            X[row][c4 * 4 + 2] = vx.z; X[row][c4 * 4 + 3] = vx.w;
            nacc += vx.x * vx.x + vx.y * vx.y + vx.z * vx.z + vx.w * vx.w;
            float4 vy = *(const float4*)&R[(size_t)(b * 64 + row) * 1024 + a64 + c4 * 4];
            Y[row][c4 * 4 + 0] = vy.x; Y[row][c4 * 4 + 1] = vy.y;
            Y[row][c4 * 4 + 2] = vy.z; Y[row][c4 * 4 + 3] = vy.w;
        }
        __syncthreads();
#pragma unroll
        for (int s = 0; s < 16; ++s) {
            float xv = X[i][g * 16 + s];
            float yv = Y[g * 16 + s][i];
            float d = xv - yv;
            tacc += d * d;
        }
    }
    tacc += __shfl_xor(tacc, 1);
    tacc += __shfl_xor(tacc, 2);
    if (g == 0) T[((ts * 4 + rb) << 10) + a64 + i] = tacc;
    for (int off = 32; off > 0; off >>= 1) nacc += __shfl_down(nacc, off);
    if ((t & 63) == 0) atomicAdd(&nrm2[ts * 4 + rb], nacc);
}

// ---------------- K4: v[i] = c * prod_ts (1 - 0.5*scale^2*T) ----------------
__global__ void vbuild(const float* __restrict__ T, const float* __restrict__ nrm2,
                       const int* __restrict__ info_i, const float* __restrict__ info_f,
                       float* __restrict__ v) {
    const int i = blockIdx.x * 256 + threadIdx.x;
    const int k = info_i[2];
    const float c = info_f[3];
    const int rb = i >> 10, di = i & 1023;
    const float eps = 1e-5f * 1024.0f * 1024.0f / 2.0f;
    float q = c;
    for (int ts = 0; ts < k; ++ts) {
        float nrm = sqrtf(nrm2[ts * 4 + rb]);
        float scale = (nrm <= eps) ? 1.0f : eps / fmaxf(nrm, 1e-12f);
        q *= 1.0f - 0.5f * scale * scale * T[((ts * 4 + rb) << 10) + di];
    }
    v[i] = q;
}

// ---------------- K5: Wv[o][i] = bf16(W[o][i] * v[i]) ----------------
__global__ void scaleW(const float4* __restrict__ W4, const float* __restrict__ v,
                       bf16* __restrict__ Wv) {
    const size_t stride = (size_t)gridDim.x * blockDim.x;
    for (size_t i = (size_t)blockIdx.x * blockDim.x + threadIdx.x; i < (size_t)4096 * 1024; i += stride) {
        float4 w = W4[i];
        const float* vp = &v[(i & 1023) << 2];
        bf16x4 o;
        o[0] = (bf16)(w.x * vp[0]);
        o[1] = (bf16)(w.y * vp[1]);
        o[2] = (bf16)(w.z * vp[2]);
        o[3] = (bf16)(w.w * vp[3]);
        *(bf16x4*)&Wv[i << 2] = o;
    }
}

// ---------------- K6: 256^2-tile 8-phase bf16 GEMM, C = A @ B^T (f32 out) ----------------
__device__ __forceinline__ void gload_lds16(const bf16* g, bf16* lds) {
    __builtin_amdgcn_global_load_lds((const AS1 void*)g, (AS3 void*)lds, 16, 0, 0);
}

__global__ __launch_bounds__(512, 2) void gemm256(const bf16* __restrict__ A,
                                                  const bf16* __restrict__ B,
                                                  float* __restrict__ C) {
    __shared__ bf16 lds[65536];   // 128 KiB: 2 buffers x (A 32KB + B 32KB)
    const int t = threadIdx.x;
    const int w = t >> 6, l = t & 63;
    // T1: bijective XCD swizzle (256 wgs, 256 % 8 == 0)
    const int bid = blockIdx.x;
    const int swz = ((bid & 7) << 5) | (bid >> 3);
    const int bm = swz >> 4, bn = swz & 15;
    const int wm = w >> 2, wn = w & 3;          // 2M x 4N waves
    const int rl = l & 15, q = l >> 4;
    const int xm = (l & 7) << 4;                // T2 swizzle mask (byte bits 4-6)

    // staging: lane covers 16B; row = 16w + 8i + (l>>3); global col pre-swizzled (rule #21)
    const int srow = (w << 4) + (l >> 3);
    const int scol = ((l & 7) ^ (l >> 3)) << 3;     // bf16 elements
    const bf16* pA = A + (size_t)((bm << 8) + srow) * 4096 + scol;
    const bf16* pB = B + (size_t)((bn << 8) + srow) * 4096 + scol;

    // one half-tile (128 rows x 64 cols x 2B = 16KB) = 2 loads/wave, lds dest LINEAR
#define STG(dstE, srcP, h, kt) do {                                                          \
        gload_lds16((srcP) + (size_t)((h) * 128) * 4096 + (size_t)(kt) * 64,                 \
                    (bf16*)&lds[(dstE) + (h) * 8192 + w * 1024]);                            \
        gload_lds16((srcP) + (size_t)((h) * 128 + 8) * 4096 + (size_t)(kt) * 64,             \
                    (bf16*)&lds[(dstE) + (h) * 8192 + w * 1024 + 512]);                      \
    } while (0)

    // fragment read offsets (elements); swizzled col slots
    const int aB = (((wm << 7) + rl) << 6);
    const int bB = 16384 + (((wn << 6) + rl) << 6);
    const int c0 = (((q << 4) + 0) ^ xm) >> 1;     // k-slice 0
    const int c1 = (((q << 4) + 64) ^ xm) >> 1;    // k-slice 1

    f32x4 acc[8][4] = {};

    // prologue stages: A0(0) A1(0) B0(0) B1(0) A0(1) A1(1)  (12 loads/wave)
    STG(0, pA, 0, 0); STG(0, pA, 1, 0);
    STG(16384, pB, 0, 0); STG(16384, pB, 1, 0);
    STG(32768, pA, 0, 1); STG(32768, pA, 1, 1);

    for (int kt = 0; kt < 64; ++kt) {
        const int bufE = (kt & 1) << 15;
        const int nb = bufE ^ 32768;
        // T4: counted vmcnt — this tile's 8 loads landed, next tile's A (4) still in flight
        if (kt < 63) asm volatile("s_waitcnt vmcnt(4)" ::: "memory");
        else         asm volatile("s_waitcnt vmcnt(0)" ::: "memory");
        __builtin_amdgcn_s_barrier();
        asm volatile("" ::: "memory");   // no load hoisting above the barrier

        bf16x8 a0[8], b0[4], a1[8], b1[4];
        // ---- phase 0: read k-slice 0 (12 x ds_read_b128), stage B-half0(kt+1), MFMA m0-3
#pragma unroll
        for (int m = 0; m < 8; ++m) a0[m] = *(const bf16x8*)&lds[bufE + aB + m * 1024 + c0];
#pragma unroll
        for (int n = 0; n < 4; ++n) b0[n] = *(const bf16x8*)&lds[bufE + bB + n * 1024 + c0];
        if (kt + 1 < 64) STG(nb + 16384, pB, 0, kt + 1);
        __builtin_amdgcn_s_setprio(1);
#pragma unroll
        for (int m = 0; m < 4; ++m)
#pragma unroll
            for (int n = 0; n < 4; ++n)
                acc[m][n] = __builtin_amdgcn_mfma_f32_16x16x32_bf16(a0[m], b0[n], acc[m][n], 0, 0, 0);
        __builtin_amdgcn_s_setprio(0);
        __builtin_amdgcn_s_barrier();

        // ---- phase 1: read k-slice 1, stage B-half1(kt+1), MFMA m4-7 (k-slice 0)
#pragma unroll
        for (int m = 0; m < 8; ++m) a1[m] = *(const bf16x8*)&lds[bufE + aB + m * 1024 + c1];
#pragma unroll
        for (int n = 0; n < 4; ++n) b1[n] = *(const bf16x8*)&lds[bufE + bB + n * 1024 + c1];
        if (kt + 1 < 64) STG(nb + 16384, pB, 1, kt + 1);
        __builtin_amdgcn_s_setprio(1);
#pragma unroll
        for (int m = 4; m < 8; ++m)
#pragma unroll
            for (int n = 0; n < 4; ++n)
                acc[m][n] = __builtin_amdgcn_mfma_f32_16x16x32_bf16(a0[m], b0[n], acc[m][n], 0, 0, 0);
        __builtin_amdgcn_s_setprio(0);
        // drain ALL this-tile LDS reads before any wave may overwrite A region (phase 2)
        asm volatile("s_waitcnt lgkmcnt(0)" ::: "memory");
        __builtin_amdgcn_s_barrier();

        // ---- phase 2: stage A-half0(kt+2) into THIS buffer (reads drained), MFMA m0-3 k1
        if (kt + 2 < 64) STG(bufE, pA, 0, kt + 2);
        __builtin_amdgcn_s_setprio(1);
#pragma unroll
        for (int m = 0; m < 4; ++m)
#pragma unroll
            for (int n = 0; n < 4; ++n)
                acc[m][n] = __builtin_amdgcn_mfma_f32_16x16x32_bf16(a1[m], b1[n], acc[m][n], 0, 0, 0);
        __builtin_amdgcn_s_setprio(0);
        __builtin_amdgcn_s_barrier();

        // ---- phase 3: stage A-half1(kt+2), MFMA m4-7 k1
        if (kt + 2 < 64) STG(bufE, pA, 1, kt + 2);
        __builtin_amdgcn_s_setprio(1);
#pragma unroll
        for (int m = 4; m < 8; ++m)
#pragma unroll
            for (int n = 0; n < 4; ++n)
                acc[m][n] = __builtin_amdgcn_mfma_f32_16x16x32_bf16(a1[m], b1[n], acc[m][n], 0, 0, 0);
        __builtin_amdgcn_s_setprio(0);
        // tile-top vmcnt+barrier of next iteration closes this tile
    }
#undef STG

    // epilogue: C row = 16m + 4q + r, col = 16n + rl (m89 layout)
    const int crow = (bm << 8) + (wm << 7) + (q << 2);
    const int ccol = (bn << 8) + (wn << 6) + rl;
#pragma unroll
    for (int m = 0; m < 8; ++m)
#pragma unroll
        for (int n = 0; n < 4; ++n)
#pragma unroll
            for (int r = 0; r < 4; ++r)
                C[(size_t)(crow + m * 16 + r) * 4096 + ccol + n * 16] = acc[m][n][r];
}

extern "C" void kernel_launch(void* const* d_in, const int* in_sizes, int n_in,
                              void* d_out, int out_size, void* d_ws, size_t ws_size,
                              hipStream_t stream) {
    const float* input      = (const float*)d_in[0];
    const float* lora_route = (const float*)d_in[1];
    const float* lora_down  = (const float*)d_in[2];
    const float* W          = (const float*)d_in[3];
    const int*   task_id    = (const int*)d_in[4];

    char* ws = (char*)d_ws;
    bf16*  inbf    = (bf16*)(ws + OFF_INBF);
    bf16*  Wv      = (bf16*)(ws + OFF_WV);
    float* meansum = (float*)(ws + OFF_MEAN);
    float* T       = (float*)(ws + OFF_T);
    float* nrm2    = (float*)(ws + OFF_NRM2);
    int*   info_i  = (int*)(ws + OFF_INFO);
    float* info_f  = (float*)(ws + OFF_INFO);
    float* v       = (float*)(ws + OFF_V);
    float* out     = (float*)d_out;

    hipMemsetAsync(ws + OFF_MEAN, 0, OFF_V + 4096 * 4 - OFF_MEAN, stream);

    mean_cvt<<<dim3(4, 128), 256, 0, stream>>>((const float4*)input, meansum, inbf);
    omega_kernel<<<1, 256, 0, stream>>>(meansum, lora_route, task_id, info_i, info_f);
    diag_kernel<<<128, 256, 0, stream>>>(lora_down, info_i, T, nrm2);
    vbuild<<<16, 256, 0, stream>>>(T, nrm2, info_i, info_f, v);
    scaleW<<<4096, 256, 0, stream>>>((const float4*)W, v, Wv);
    gemm256<<<256, 512, 0, stream>>>(inbf, Wv, out);
}